// Round 8
// baseline (774.170 us; speedup 1.0000x reference)
//
#include <hip/hip_runtime.h>
#include <math.h>

#define RR 3
#define NTOT 100000
#define NN0 80000
#define NN1 20000
#define NB 4096
#define NE1 300000
#define NE2 65536
#define FIN 128
#define HC1 256   // layer1: 2 heads x 128
#define HC2 128   // layer2: 1 head x 128

typedef __attribute__((ext_vector_type(8))) short bf16x8;
typedef __attribute__((ext_vector_type(4))) short s16x4;
typedef __attribute__((ext_vector_type(2))) short s16x2;
typedef __attribute__((ext_vector_type(4))) float f32x4;

struct f8 { float v[8]; };

__device__ __forceinline__ float wave_red_sum(float v) {
    #pragma unroll
    for (int off = 32; off >= 1; off >>= 1) v += __shfl_xor(v, off, 64);
    return v;
}

__device__ __forceinline__ short f2bf(float x) {
    union { float f; unsigned u; } c; c.f = x;
    unsigned r = c.u + 0x7fffu + ((c.u >> 16) & 1u);
    return (short)(r >> 16);
}
__device__ __forceinline__ float bf2f(short s) {
    union { unsigned u; float f; } c; c.u = ((unsigned)(unsigned short)s) << 16;
    return c.f;
}
__device__ __forceinline__ f8 cvt8(uint4 u) {
    f8 r;
    r.v[0] = __uint_as_float(u.x << 16); r.v[1] = __uint_as_float(u.x & 0xffff0000u);
    r.v[2] = __uint_as_float(u.y << 16); r.v[3] = __uint_as_float(u.y & 0xffff0000u);
    r.v[4] = __uint_as_float(u.z << 16); r.v[5] = __uint_as_float(u.z & 0xffff0000u);
    r.v[6] = __uint_as_float(u.w << 16); r.v[7] = __uint_as_float(u.w & 0xffff0000u);
    return r;
}

__device__ __forceinline__ float4 ld4(const float* p) { return *(const float4*)p; }
__device__ __forceinline__ float4 ld4(const short* p) {
    s16x4 v = *(const s16x4*)p;
    float4 r = { bf2f(v[0]), bf2f(v[1]), bf2f(v[2]), bf2f(v[3]) };
    return r;
}

// ---------- convert features f32 -> bf16 ----------
__global__ void __launch_bounds__(256)
fcvt_k(const float* __restrict__ f, short* __restrict__ o, int n4) {
    int i = blockIdx.x * 256 + threadIdx.x;
    if (i < n4) {
        float4 v = *(const float4*)(f + (size_t)i * 4);
        s16x4 s = { f2bf(v.x), f2bf(v.y), f2bf(v.z), f2bf(v.w) };
        *(s16x4*)(o + (size_t)i * 4) = s;
    }
}

// ---------- pack 4 weight mats per replica into MFMA B-fragment order ----------
template<int K, int N>
__global__ void __launch_bounds__(256)
wpack_k(const float* __restrict__ W0, const float* __restrict__ W1,
        const float* __restrict__ W2, const float* __restrict__ W3,
        short* __restrict__ P) {
    constexpr int KS = K / 32;
    const int m = blockIdx.y, r = blockIdx.z;
    const float* W = (m == 0 ? W0 : m == 1 ? W1 : m == 2 ? W2 : W3) + (size_t)r * K * N;
    short* o = P + ((size_t)(r * 4 + m)) * K * N;
    for (int i = blockIdx.x * 256 + threadIdx.x; i < K * N; i += gridDim.x * 256) {
        int j = i & 7, lane = (i >> 3) & 63, f = i >> 9;
        int ks = f % KS, nt = f / KS;
        int k = ks * 32 + (lane >> 4) * 8 + j;
        int n = nt * 16 + (lane & 15);
        o[i] = f2bf(W[(size_t)k * N + n]);
    }
}

// ---------- MFMA GEMM, low-pressure tiling; per-output row stride (ldo) ----------
template<int K, int N, typename OT0, typename OT1>
__global__ void __launch_bounds__(256)
gemm2l(const short* __restrict__ xbf, int ldx, const int* __restrict__ gidx,
       const short* __restrict__ P0, const float* __restrict__ b0, OT0* __restrict__ out0, int ldo0,
       const short* __restrict__ P1, const float* __restrict__ b1, OT1* __restrict__ out1, int ldo1)
{
    constexpr int NT = N / 16;
    constexpr int NW = NT / 4;
    constexpr int KS = K / 32;
    constexpr int MT = 2;
    const int lane = threadIdx.x & 63;
    const int wid  = threadIdx.x >> 6;
    const int rowbase = blockIdx.x * (MT * 16);

    const short* ap[MT];
    #pragma unroll
    for (int mt = 0; mt < MT; ++mt) {
        int arow = rowbase + mt * 16 + (lane & 15);
        int srow = gidx ? gidx[arow] : arow;
        ap[mt] = xbf + (size_t)srow * ldx + ((lane >> 4) * 8);
    }
    const int fb = lane * 8;

    f32x4 acc[MT][NW][2];
    #pragma unroll
    for (int mt = 0; mt < MT; ++mt)
        #pragma unroll
        for (int j = 0; j < NW; ++j) { acc[mt][j][0] = (f32x4)(0.0f); acc[mt][j][1] = (f32x4)(0.0f); }

    for (int ks = 0; ks < KS; ++ks) {
        bf16x8 a[MT];
        #pragma unroll
        for (int mt = 0; mt < MT; ++mt) a[mt] = *(const bf16x8*)(ap[mt] + ks * 32);
        #pragma unroll
        for (int j = 0; j < NW; ++j) {
            const int nt = wid * NW + j;
            const int off = ((nt * KS + ks) << 9) + fb;
            bf16x8 bv0 = *(const bf16x8*)(P0 + off);
            bf16x8 bv1 = *(const bf16x8*)(P1 + off);
            #pragma unroll
            for (int mt = 0; mt < MT; ++mt) {
                acc[mt][j][0] = __builtin_amdgcn_mfma_f32_16x16x32_bf16(a[mt], bv0, acc[mt][j][0], 0, 0, 0);
                acc[mt][j][1] = __builtin_amdgcn_mfma_f32_16x16x32_bf16(a[mt], bv1, acc[mt][j][1], 0, 0, 0);
            }
        }
    }

    __shared__ float ls[MT * 16][N + 4];
    constexpr int CPT = (MT * 16) * N / 8 / 256;
    const int tid = threadIdx.x;

    #pragma unroll
    for (int mat = 0; mat < 2; ++mat) {
        if (mat) __syncthreads();
        const float* bias = mat ? b1 : b0;
        #pragma unroll
        for (int j = 0; j < NW; ++j) {
            const int nt = wid * NW + j;
            const float bb = bias[nt * 16 + (lane & 15)];
            #pragma unroll
            for (int mt = 0; mt < MT; ++mt)
                #pragma unroll
                for (int rg = 0; rg < 4; ++rg)
                    ls[mt * 16 + (lane >> 4) * 4 + rg][nt * 16 + (lane & 15)] =
                        acc[mt][j][mat][rg] + bb;
        }
        __syncthreads();
        #pragma unroll
        for (int c2 = 0; c2 < CPT; ++c2) {
            const int chunk = c2 * 256 + tid;
            const int row = chunk / (N / 8);
            const int colb = (chunk % (N / 8)) * 8;
            float v[8];
            #pragma unroll
            for (int i = 0; i < 8; ++i) v[i] = ls[row][colb + i];
            if (mat == 0) {
                const size_t gbase = (size_t)(rowbase + row) * ldo0 + colb;
                if constexpr (sizeof(OT0) == 2) {
                    bf16x8 s;
                    #pragma unroll
                    for (int i = 0; i < 8; ++i) s[i] = f2bf(v[i]);
                    *(bf16x8*)(out0 + gbase) = s;
                } else {
                    float4 lo = { v[0], v[1], v[2], v[3] }, hi = { v[4], v[5], v[6], v[7] };
                    *(float4*)(out0 + gbase) = lo;
                    *(float4*)(out0 + gbase + 4) = hi;
                }
            } else {
                const size_t gbase = (size_t)(rowbase + row) * ldo1 + colb;
                if constexpr (sizeof(OT1) == 2) {
                    bf16x8 s;
                    #pragma unroll
                    for (int i = 0; i < 8; ++i) s[i] = f2bf(v[i]);
                    *(bf16x8*)(out1 + gbase) = s;
                } else {
                    float4 lo = { v[0], v[1], v[2], v[3] }, hi = { v[4], v[5], v[6], v[7] };
                    *(float4*)(out1 + gbase) = lo;
                    *(float4*)(out1 + gbase + 4) = hi;
                }
            }
        }
    }
}

// ---------- CSR helpers (scatter stores src id directly) ----------
__global__ void hist_k(const int* __restrict__ dst, int E, int* __restrict__ cnt) {
    for (int e = blockIdx.x*blockDim.x + threadIdx.x; e < E; e += gridDim.x*blockDim.x)
        atomicAdd(&cnt[dst[e]], 1);
}
__global__ void __launch_bounds__(256)
exscan_k(const int* __restrict__ cnt, int n, int* __restrict__ offs, int* __restrict__ cur) {
    __shared__ int ps[256];
    const int tid = threadIdx.x;
    const int chunk = (n + 255) / 256;
    const int lo = tid * chunk;
    const int hi = min(lo + chunk, n);
    int s = 0;
    for (int i = lo; i < hi; ++i) s += cnt[i];
    ps[tid] = s;
    __syncthreads();
    for (int off = 1; off < 256; off <<= 1) {
        int v = (tid >= off) ? ps[tid - off] : 0;
        __syncthreads();
        ps[tid] += v;
        __syncthreads();
    }
    int run = (tid == 0) ? 0 : ps[tid - 1];
    for (int i = lo; i < hi; ++i) { offs[i] = run; cur[i] = run; run += cnt[i]; }
    if (tid == 255) offs[n] = ps[255];
}
__global__ void scatter_k(const int* __restrict__ src, const int* __restrict__ dst, int E,
                          int* __restrict__ cur, int* __restrict__ slist) {
    for (int e = blockIdx.x*blockDim.x + threadIdx.x; e < E; e += gridDim.x*blockDim.x) {
        int pos = atomicAdd(&cur[dst[e]], 1);
        slist[pos] = src[e];
    }
}

// ---------- fused layer-1 attention (no-max softmax, 8ch/lane, 2 edges/wave) ----------
// lanes 0-31: even edges, lanes 32-63: odd edges; within half: 16-lane group per head.
// lane's channels: c0 = (lane&31)*8 (covers both heads across 32 lanes).
__global__ void __launch_bounds__(64)
attn1_k(const int* __restrict__ offs, const int* __restrict__ slist,
        const short* __restrict__ qb, const short* __restrict__ kb, const short* __restrict__ vb,
        const float* __restrict__ xr, const float* __restrict__ wb,
        const float* __restrict__ g, const float* __restrict__ bbn,
        const float* __restrict__ mean, const float* __restrict__ var,
        short* __restrict__ hb)
{
    const int n = blockIdx.x;
    const int lane = threadIdx.x;
    const int epar = lane >> 5;          // 0: even edges, 1: odd edges
    const int c0 = (lane & 31) * 8;
    const int lo = offs[n], hi = offs[n+1];
    const float scale = 0.088388347648318447f;   // 1/sqrt(128)

    f8 q = cvt8(*(const uint4*)(qb + (size_t)n * HC1 + c0));
    #pragma unroll
    for (int j = 0; j < 8; ++j) q.v[j] *= scale;

    float s = 0.f;
    float a[8];
    #pragma unroll
    for (int j = 0; j < 8; ++j) a[j] = 0.f;

    int i = lo + epar;
    uint4 kr, vr;
    if (i < hi) {
        const size_t rb = (size_t)slist[i] * HC1 + c0;
        kr = *(const uint4*)(kb + rb); vr = *(const uint4*)(vb + rb);
    }
    for (; i < hi; i += 2) {
        uint4 krn, vrn;
        if (i + 2 < hi) {
            const size_t rb = (size_t)slist[i + 2] * HC1 + c0;
            krn = *(const uint4*)(kb + rb); vrn = *(const uint4*)(vb + rb);
        }
        f8 k = cvt8(kr);
        float part = 0.f;
        #pragma unroll
        for (int j = 0; j < 8; ++j) part += q.v[j] * k.v[j];
        #pragma unroll
        for (int off = 8; off >= 1; off >>= 1) part += __shfl_xor(part, off, 64);
        const float p = __expf(part);        // |part| small: no-max softmax is safe
        f8 v = cvt8(vr);
        s += p;
        #pragma unroll
        for (int j = 0; j < 8; ++j) a[j] += p * v.v[j];
        kr = krn; vr = vrn;
    }
    // combine even/odd halves (exact duplicate on both halves afterward)
    s += __shfl_xor(s, 32, 64);
    #pragma unroll
    for (int j = 0; j < 8; ++j) a[j] += __shfl_xor(a[j], 32, 64);

    const float inv = (s > 0.f) ? 1.f/s : 0.f;
    float att[8];
    #pragma unroll
    for (int j = 0; j < 8; ++j) att[j] = a[j] * inv;

    // beta gate (each channel counted twice across the wave -> halve)
    float x[8];
    {
        float4 xlo = ld4(xr + (size_t)n * HC1 + c0);
        float4 xhi = ld4(xr + (size_t)n * HC1 + c0 + 4);
        x[0]=xlo.x; x[1]=xlo.y; x[2]=xlo.z; x[3]=xlo.w;
        x[4]=xhi.x; x[5]=xhi.y; x[6]=xhi.z; x[7]=xhi.w;
    }
    float dp = 0.f;
    #pragma unroll
    for (int j = 0; j < 8; ++j) {
        int c = c0 + j;
        dp += att[j]*wb[c] + x[j]*wb[HC1 + c] + (att[j]-x[j])*wb[2*HC1 + c];
    }
    const float d = 0.5f * wave_red_sum(dp);
    const float beta = 1.f / (1.f + __expf(-d));

    if (lane < 32) {
        bf16x8 hv;
        #pragma unroll
        for (int j = 0; j < 8; ++j) {
            int c = c0 + j;
            float h = beta*x[j] + (1.f-beta)*att[j];
            h = (h - mean[c]) * rsqrtf(var[c] + 1e-5f) * g[c] + bbn[c];
            h = h > 0.f ? h : expm1f(h);
            hv[j] = f2bf(h);
        }
        *(bf16x8*)(hb + (size_t)n * HC1 + c0) = hv;
    }
}

// ---------- fused layer-2 attention (no-max softmax, 8ch/lane, 4 edges/wave) ----------
// 16-lane group per edge; lane's channels: c0 = (lane&15)*8.
__global__ void __launch_bounds__(64)
attn2_k(const int* __restrict__ offs, const int* __restrict__ slist,
        const short* __restrict__ qb, const short* __restrict__ kb, const short* __restrict__ vb,
        const float* __restrict__ xr, const float* __restrict__ wb,
        float* __restrict__ outp, int colofs)
{
    const int n = blockIdx.x;
    const int lane = threadIdx.x;
    const int epar = lane >> 4;          // 0..3
    const int c0 = (lane & 15) * 8;
    const int lo = offs[n], hi = offs[n+1];
    const float scale = 0.088388347648318447f;   // 1/sqrt(128)

    f8 q = cvt8(*(const uint4*)(qb + (size_t)n * HC2 + c0));
    #pragma unroll
    for (int j = 0; j < 8; ++j) q.v[j] *= scale;

    float s = 0.f;
    float a[8];
    #pragma unroll
    for (int j = 0; j < 8; ++j) a[j] = 0.f;

    int i = lo + epar;
    uint4 kr, vr;
    if (i < hi) {
        const size_t rb = (size_t)slist[i] * HC2 + c0;
        kr = *(const uint4*)(kb + rb); vr = *(const uint4*)(vb + rb);
    }
    for (; i < hi; i += 4) {
        uint4 krn, vrn;
        if (i + 4 < hi) {
            const size_t rb = (size_t)slist[i + 4] * HC2 + c0;
            krn = *(const uint4*)(kb + rb); vrn = *(const uint4*)(vb + rb);
        }
        f8 k = cvt8(kr);
        float part = 0.f;
        #pragma unroll
        for (int j = 0; j < 8; ++j) part += q.v[j] * k.v[j];
        #pragma unroll
        for (int off = 8; off >= 1; off >>= 1) part += __shfl_xor(part, off, 64);
        const float p = __expf(part);
        f8 v = cvt8(vr);
        s += p;
        #pragma unroll
        for (int j = 0; j < 8; ++j) a[j] += p * v.v[j];
        kr = krn; vr = vrn;
    }
    // combine 4 groups (exact duplicates afterward)
    s += __shfl_xor(s, 16, 64);
    s += __shfl_xor(s, 32, 64);
    #pragma unroll
    for (int j = 0; j < 8; ++j) {
        a[j] += __shfl_xor(a[j], 16, 64);
        a[j] += __shfl_xor(a[j], 32, 64);
    }

    const float inv = (s > 0.f) ? 1.f/s : 0.f;
    float att[8];
    #pragma unroll
    for (int j = 0; j < 8; ++j) att[j] = a[j] * inv;

    float x[8];
    {
        float4 xlo = ld4(xr + (size_t)n * HC2 + c0);
        float4 xhi = ld4(xr + (size_t)n * HC2 + c0 + 4);
        x[0]=xlo.x; x[1]=xlo.y; x[2]=xlo.z; x[3]=xlo.w;
        x[4]=xhi.x; x[5]=xhi.y; x[6]=xhi.z; x[7]=xhi.w;
    }
    float dp = 0.f;
    #pragma unroll
    for (int j = 0; j < 8; ++j) {
        int c = c0 + j;
        dp += att[j]*wb[c] + x[j]*wb[HC2 + c] + (att[j]-x[j])*wb[2*HC2 + c];
    }
    const float d = 0.25f * wave_red_sum(dp);   // each channel counted 4x
    const float beta = 1.f/(1.f+__expf(-d));

    if (lane < 16) {
        float o[8];
        #pragma unroll
        for (int j = 0; j < 8; ++j) o[j] = beta*x[j] + (1.f-beta)*att[j];
        float* op = outp + (size_t)n*(RR*HC2) + colofs + c0;
        float4 olo = { o[0], o[1], o[2], o[3] }, ohi = { o[4], o[5], o[6], o[7] };
        *(float4*)op = olo;
        *(float4*)(op + 4) = ohi;
    }
}

extern "C" void kernel_launch(void* const* d_in, const int* in_sizes, int n_in,
                              void* d_out, int out_size, void* d_ws, size_t ws_size,
                              hipStream_t stream)
{
    const float* features = (const float*)d_in[0];
    const int*   n_ids    = (const int*)d_in[1];
    const int*   ei1      = (const int*)d_in[2];
    const int*   ei2      = (const int*)d_in[3];
    const float* wq1 = (const float*)d_in[4];  const float* bq1 = (const float*)d_in[5];
    const float* wk1 = (const float*)d_in[6];  const float* bk1 = (const float*)d_in[7];
    const float* wv1 = (const float*)d_in[8];  const float* bv1 = (const float*)d_in[9];
    const float* ws1 = (const float*)d_in[10]; const float* bs1 = (const float*)d_in[11];
    const float* wbeta1 = (const float*)d_in[12];
    const float* bn_g = (const float*)d_in[13]; const float* bn_b = (const float*)d_in[14];
    const float* bn_m = (const float*)d_in[15]; const float* bn_v = (const float*)d_in[16];
    const float* wq2 = (const float*)d_in[17]; const float* bq2 = (const float*)d_in[18];
    const float* wk2 = (const float*)d_in[19]; const float* bk2 = (const float*)d_in[20];
    const float* wv2 = (const float*)d_in[21]; const float* bv2 = (const float*)d_in[22];
    const float* ws2 = (const float*)d_in[23]; const float* bs2 = (const float*)d_in[24];
    const float* wbeta2 = (const float*)d_in[25];
    float* outp = (float*)d_out;

    char* p = (char*)d_ws;
    auto alloc = [&](size_t bytes) { char* q = p; p += (bytes + 255) & ~(size_t)255; return q; };
    short* k1b  = (short*)alloc(sizeof(short)*(size_t)NN0*HC1);   // 41 MB
    short* v1b  = (short*)alloc(sizeof(short)*(size_t)NN0*HC1);   // 41 MB
    short* q1b  = (short*)alloc(sizeof(short)*(size_t)NN1*HC1);   // 10.2 MB
    float* xr1  = (float*)alloc(sizeof(float)*(size_t)NN1*HC1);   // 20.5 MB
    short* hbf  = (short*)alloc(sizeof(short)*(size_t)NN1*HC1);   // 10.2 MB
    short* xbf  = (short*)alloc(sizeof(short)*(size_t)NTOT*FIN);  // 25.6 MB
    short* wt1  = (short*)alloc(sizeof(short)*(size_t)RR*4*FIN*HC1);
    short* wt2  = (short*)alloc(sizeof(short)*(size_t)RR*4*HC1*HC2);
    short* k2b  = (short*)alloc(sizeof(short)*(size_t)NN1*HC2);
    short* v2b  = (short*)alloc(sizeof(short)*(size_t)NN1*HC2);
    short* q2b  = (short*)alloc(sizeof(short)*(size_t)NB*HC2);
    float* xr2  = (float*)alloc(sizeof(float)*(size_t)NB*HC2);
    int* cnt1   = (int*)alloc(sizeof(int)*NN1);
    int* offs1  = (int*)alloc(sizeof(int)*(NN1+1));
    int* cur1   = (int*)alloc(sizeof(int)*NN1);
    int* slist1 = (int*)alloc(sizeof(int)*NE1);
    int* cnt2   = (int*)alloc(sizeof(int)*NB);
    int* offs2  = (int*)alloc(sizeof(int)*(NB+1));
    int* cur2   = (int*)alloc(sizeof(int)*NB);
    int* slist2 = (int*)alloc(sizeof(int)*NE2);
    (void)ws_size; (void)in_sizes; (void)n_in; (void)out_size;

    // ---- prologue: dtype conversions + fragment packing (once per launch) ----
    fcvt_k<<<(NTOT*FIN/4 + 255)/256, 256, 0, stream>>>(features, xbf, NTOT*FIN/4);
    {
        dim3 g1(128, 4, RR);
        wpack_k<FIN, HC1><<<g1, 256, 0, stream>>>(wq1, wk1, wv1, ws1, wt1);
        dim3 g2(128, 4, RR);
        wpack_k<HC1, HC2><<<g2, 256, 0, stream>>>(wq2, wk2, wv2, ws2, wt2);
    }
    const size_t WSZ = (size_t)FIN*HC1;

    for (int r = 0; r < RR; ++r) {
        const int* nid  = n_ids + (size_t)r*NN0;
        const int* src1 = ei1 + (size_t)r*2*NE1;
        const int* dst1 = src1 + NE1;
        const int* src2 = ei2 + (size_t)r*2*NE2;
        const int* dst2 = src2 + NE2;
        const short* ptq1 = wt1 + ((size_t)r*4 + 0)*WSZ;
        const short* ptk1 = wt1 + ((size_t)r*4 + 1)*WSZ;
        const short* ptv1 = wt1 + ((size_t)r*4 + 2)*WSZ;
        const short* pts1 = wt1 + ((size_t)r*4 + 3)*WSZ;
        const short* ptq2 = wt2 + ((size_t)r*4 + 0)*WSZ;
        const short* ptk2 = wt2 + ((size_t)r*4 + 1)*WSZ;
        const short* ptv2 = wt2 + ((size_t)r*4 + 2)*WSZ;
        const short* pts2 = wt2 + ((size_t)r*4 + 3)*WSZ;

        // ---- layer 1 CSR ----
        hipMemsetAsync(cnt1, 0, sizeof(int)*NN1, stream);
        hist_k<<<512, 256, 0, stream>>>(dst1, NE1, cnt1);
        exscan_k<<<1, 256, 0, stream>>>(cnt1, NN1, offs1, cur1);
        scatter_k<<<512, 256, 0, stream>>>(src1, dst1, NE1, cur1, slist1);

        // ---- layer 1 projections (MFMA, fused gather, bf16 out) ----
        gemm2l<FIN, HC1, short, short><<<NN0/32, 256, 0, stream>>>(
            xbf, FIN, nid, ptk1, bk1 + r*HC1, k1b, HC1, ptv1, bv1 + r*HC1, v1b, HC1);
        gemm2l<FIN, HC1, short, float><<<NN1/32, 256, 0, stream>>>(
            xbf, FIN, nid, ptq1, bq1 + r*HC1, q1b, HC1, pts1, bs1 + r*HC1, xr1, HC1);

        // ---- layer 1 fused attention + epilogue ----
        attn1_k<<<NN1, 64, 0, stream>>>(offs1, slist1, q1b, k1b, v1b, xr1,
            wbeta1 + (size_t)r*3*HC1,
            bn_g + (size_t)r*HC1, bn_b + (size_t)r*HC1,
            bn_m + (size_t)r*HC1, bn_v + (size_t)r*HC1, hbf);

        // ---- layer 2 CSR ----
        hipMemsetAsync(cnt2, 0, sizeof(int)*NB, stream);
        hist_k<<<256, 256, 0, stream>>>(dst2, NE2, cnt2);
        exscan_k<<<1, 256, 0, stream>>>(cnt2, NB, offs2, cur2);
        scatter_k<<<256, 256, 0, stream>>>(src2, dst2, NE2, cur2, slist2);

        // ---- layer 2 projections (MFMA, bf16 out for k/v/q) ----
        gemm2l<HC1, HC2, short, short><<<NN1/32, 256, 0, stream>>>(
            hbf, HC1, nullptr, ptk2, bk2 + r*HC2, k2b, HC2, ptv2, bv2 + r*HC2, v2b, HC2);
        gemm2l<HC1, HC2, short, float><<<NB/32, 256, 0, stream>>>(
            hbf, HC1, nullptr, ptq2, bq2 + r*HC2, q2b, HC2, pts2, bs2 + r*HC2, xr2, HC2);

        // ---- layer 2 fused attention + output ----
        attn2_k<<<NB, 64, 0, stream>>>(offs2, slist2, q2b, k2b, v2b, xr2,
            wbeta2 + (size_t)r*3*HC2, outp, r*HC2);
    }
}

// Round 9
// 655.853 us; speedup vs baseline: 1.1804x; 1.1804x over previous
//
#include <hip/hip_runtime.h>
#include <math.h>

#define RR 3
#define NTOT 100000
#define NN0 80000
#define NN1 20000
#define NB 4096
#define NE1 300000
#define NE2 65536
#define FIN 128
#define HC1 256   // layer1: 2 heads x 128
#define HC2 128   // layer2: 1 head x 128

typedef __attribute__((ext_vector_type(8))) short bf16x8;
typedef __attribute__((ext_vector_type(4))) short s16x4;
typedef __attribute__((ext_vector_type(2))) short s16x2;
typedef __attribute__((ext_vector_type(4))) float f32x4;

__device__ __forceinline__ float wave_red_sum(float v) {
    #pragma unroll
    for (int off = 32; off >= 1; off >>= 1) v += __shfl_xor(v, off, 64);
    return v;
}

__device__ __forceinline__ short f2bf(float x) {
    union { float f; unsigned u; } c; c.f = x;
    unsigned r = c.u + 0x7fffu + ((c.u >> 16) & 1u);
    return (short)(r >> 16);
}
__device__ __forceinline__ float bf2f(short s) {
    union { unsigned u; float f; } c; c.u = ((unsigned)(unsigned short)s) << 16;
    return c.f;
}

__device__ __forceinline__ float4 ld4(const float* p) { return *(const float4*)p; }
__device__ __forceinline__ float4 ld4(const short* p) {
    s16x4 v = *(const s16x4*)p;
    float4 r = { bf2f(v[0]), bf2f(v[1]), bf2f(v[2]), bf2f(v[3]) };
    return r;
}
__device__ __forceinline__ float2 ld2(const float* p) { return *(const float2*)p; }
__device__ __forceinline__ float2 ld2(const short* p) {
    s16x2 v = *(const s16x2*)p;
    float2 r = { bf2f(v[0]), bf2f(v[1]) };
    return r;
}

// ---------- convert features f32 -> bf16 ----------
__global__ void __launch_bounds__(256)
fcvt_k(const float* __restrict__ f, short* __restrict__ o, int n4) {
    int i = blockIdx.x * 256 + threadIdx.x;
    if (i < n4) {
        float4 v = *(const float4*)(f + (size_t)i * 4);
        s16x4 s = { f2bf(v.x), f2bf(v.y), f2bf(v.z), f2bf(v.w) };
        *(s16x4*)(o + (size_t)i * 4) = s;
    }
}

// ---------- pack 4 weight mats per replica into MFMA B-fragment order ----------
template<int K, int N>
__global__ void __launch_bounds__(256)
wpack_k(const float* __restrict__ W0, const float* __restrict__ W1,
        const float* __restrict__ W2, const float* __restrict__ W3,
        short* __restrict__ P) {
    constexpr int KS = K / 32;
    const int m = blockIdx.y, r = blockIdx.z;
    const float* W = (m == 0 ? W0 : m == 1 ? W1 : m == 2 ? W2 : W3) + (size_t)r * K * N;
    short* o = P + ((size_t)(r * 4 + m)) * K * N;
    for (int i = blockIdx.x * 256 + threadIdx.x; i < K * N; i += gridDim.x * 256) {
        int j = i & 7, lane = (i >> 3) & 63, f = i >> 9;
        int ks = f % KS, nt = f / KS;
        int k = ks * 32 + (lane >> 4) * 8 + j;
        int n = nt * 16 + (lane & 15);
        o[i] = f2bf(W[(size_t)k * N + n]);
    }
}

// ---------- MFMA GEMM, low-pressure tiling ----------
template<int K, int N, typename OT0, typename OT1>
__global__ void __launch_bounds__(256)
gemm2l(const short* __restrict__ xbf, int ldx, const int* __restrict__ gidx,
       const short* __restrict__ P0, const float* __restrict__ b0, OT0* __restrict__ out0,
       const short* __restrict__ P1, const float* __restrict__ b1, OT1* __restrict__ out1)
{
    constexpr int NT = N / 16;
    constexpr int NW = NT / 4;
    constexpr int KS = K / 32;
    constexpr int MT = 2;
    const int lane = threadIdx.x & 63;
    const int wid  = threadIdx.x >> 6;
    const int rowbase = blockIdx.x * (MT * 16);

    const short* ap[MT];
    #pragma unroll
    for (int mt = 0; mt < MT; ++mt) {
        int arow = rowbase + mt * 16 + (lane & 15);
        int srow = gidx ? gidx[arow] : arow;
        ap[mt] = xbf + (size_t)srow * ldx + ((lane >> 4) * 8);
    }
    const int fb = lane * 8;

    f32x4 acc[MT][NW][2];
    #pragma unroll
    for (int mt = 0; mt < MT; ++mt)
        #pragma unroll
        for (int j = 0; j < NW; ++j) { acc[mt][j][0] = (f32x4)(0.0f); acc[mt][j][1] = (f32x4)(0.0f); }

    for (int ks = 0; ks < KS; ++ks) {
        bf16x8 a[MT];
        #pragma unroll
        for (int mt = 0; mt < MT; ++mt) a[mt] = *(const bf16x8*)(ap[mt] + ks * 32);
        #pragma unroll
        for (int j = 0; j < NW; ++j) {
            const int nt = wid * NW + j;
            const int off = ((nt * KS + ks) << 9) + fb;
            bf16x8 bv0 = *(const bf16x8*)(P0 + off);
            bf16x8 bv1 = *(const bf16x8*)(P1 + off);
            #pragma unroll
            for (int mt = 0; mt < MT; ++mt) {
                acc[mt][j][0] = __builtin_amdgcn_mfma_f32_16x16x32_bf16(a[mt], bv0, acc[mt][j][0], 0, 0, 0);
                acc[mt][j][1] = __builtin_amdgcn_mfma_f32_16x16x32_bf16(a[mt], bv1, acc[mt][j][1], 0, 0, 0);
            }
        }
    }

    __shared__ float ls[MT * 16][N + 4];
    constexpr int CPT = (MT * 16) * N / 8 / 256;
    const int tid = threadIdx.x;

    #pragma unroll
    for (int mat = 0; mat < 2; ++mat) {
        if (mat) __syncthreads();
        const float* bias = mat ? b1 : b0;
        #pragma unroll
        for (int j = 0; j < NW; ++j) {
            const int nt = wid * NW + j;
            const float bb = bias[nt * 16 + (lane & 15)];
            #pragma unroll
            for (int mt = 0; mt < MT; ++mt)
                #pragma unroll
                for (int rg = 0; rg < 4; ++rg)
                    ls[mt * 16 + (lane >> 4) * 4 + rg][nt * 16 + (lane & 15)] =
                        acc[mt][j][mat][rg] + bb;
        }
        __syncthreads();
        #pragma unroll
        for (int c2 = 0; c2 < CPT; ++c2) {
            const int chunk = c2 * 256 + tid;
            const int row = chunk / (N / 8);
            const int colb = (chunk % (N / 8)) * 8;
            float v[8];
            #pragma unroll
            for (int i = 0; i < 8; ++i) v[i] = ls[row][colb + i];
            const size_t gbase = (size_t)(rowbase + row) * N + colb;
            if (mat == 0) {
                if constexpr (sizeof(OT0) == 2) {
                    bf16x8 s;
                    #pragma unroll
                    for (int i = 0; i < 8; ++i) s[i] = f2bf(v[i]);
                    *(bf16x8*)(out0 + gbase) = s;
                } else {
                    float4 lo = { v[0], v[1], v[2], v[3] }, hi = { v[4], v[5], v[6], v[7] };
                    *(float4*)(out0 + gbase) = lo;
                    *(float4*)(out0 + gbase + 4) = hi;
                }
            } else {
                if constexpr (sizeof(OT1) == 2) {
                    bf16x8 s;
                    #pragma unroll
                    for (int i = 0; i < 8; ++i) s[i] = f2bf(v[i]);
                    *(bf16x8*)(out1 + gbase) = s;
                } else {
                    float4 lo = { v[0], v[1], v[2], v[3] }, hi = { v[4], v[5], v[6], v[7] };
                    *(float4*)(out1 + gbase) = lo;
                    *(float4*)(out1 + gbase + 4) = hi;
                }
            }
        }
    }
}

// ---------- batched CSR kernels: blockIdx.y (or .x for scan) = replica ----------
__global__ void hist_b(const int* __restrict__ ei, int E, int* __restrict__ cntg, int nbins) {
    const int r = blockIdx.y;
    const int* dst = ei + (size_t)r * 2 * E + E;
    int* cnt = cntg + (size_t)r * nbins;
    for (int e = blockIdx.x*blockDim.x + threadIdx.x; e < E; e += gridDim.x*blockDim.x)
        atomicAdd(&cnt[dst[e]], 1);
}
__global__ void __launch_bounds__(256)
exscan_b(const int* __restrict__ cntg, int n, int* __restrict__ offsg, int* __restrict__ curg) {
    const int r = blockIdx.x;
    const int* cnt = cntg + (size_t)r * n;
    int* offs = offsg + (size_t)r * (n + 1);
    int* cur  = curg  + (size_t)r * n;
    __shared__ int ps[256];
    const int tid = threadIdx.x;
    const int chunk = (n + 255) / 256;
    const int lo = tid * chunk;
    const int hi = min(lo + chunk, n);
    int s = 0;
    for (int i = lo; i < hi; ++i) s += cnt[i];
    ps[tid] = s;
    __syncthreads();
    for (int off = 1; off < 256; off <<= 1) {
        int v = (tid >= off) ? ps[tid - off] : 0;
        __syncthreads();
        ps[tid] += v;
        __syncthreads();
    }
    int run = (tid == 0) ? 0 : ps[tid - 1];
    for (int i = lo; i < hi; ++i) { offs[i] = run; cur[i] = run; run += cnt[i]; }
    if (tid == 255) offs[n] = ps[255];
}
__global__ void scatter_b(const int* __restrict__ ei, int E, int* __restrict__ curg, int nbins,
                          int* __restrict__ slistg) {
    const int r = blockIdx.y;
    const int* src = ei + (size_t)r * 2 * E;
    const int* dst = src + E;
    int* cur = curg + (size_t)r * nbins;
    int* slist = slistg + (size_t)r * E;
    for (int e = blockIdx.x*blockDim.x + threadIdx.x; e < E; e += gridDim.x*blockDim.x) {
        int pos = atomicAdd(&cur[dst[e]], 1);
        slist[pos] = src[e];
    }
}

// ---------- fused layer-1 attention, edge-PAIR pipelined (round-7 known-good) ----------
__global__ void __launch_bounds__(64)
attn1_k(const int* __restrict__ offs, const int* __restrict__ slist,
        const short* __restrict__ qb, const short* __restrict__ kb, const short* __restrict__ vb,
        const float* __restrict__ xr, const float* __restrict__ wb,
        const float* __restrict__ g, const float* __restrict__ bbn,
        const float* __restrict__ mean, const float* __restrict__ var,
        short* __restrict__ hb)
{
    const int n = blockIdx.x;
    const int lane = threadIdx.x;
    const int c0 = lane * 4;
    const int lo = offs[n], hi = offs[n+1];
    const float4 q = ld4(qb + (size_t)n * HC1 + c0);
    const float scale = 0.088388347648318447f;   // 1/sqrt(128)

    float m = -INFINITY, s = 0.f;
    float a0 = 0.f, a1 = 0.f, a2 = 0.f, a3 = 0.f;
    float4 k0 = {0,0,0,0}, v0 = {0,0,0,0}, k1 = {0,0,0,0}, v1 = {0,0,0,0};
    if (lo < hi) {
        int sr = slist[lo];
        k0 = ld4(kb + (size_t)sr * HC1 + c0); v0 = ld4(vb + (size_t)sr * HC1 + c0);
    }
    if (lo + 1 < hi) {
        int sr = slist[lo + 1];
        k1 = ld4(kb + (size_t)sr * HC1 + c0); v1 = ld4(vb + (size_t)sr * HC1 + c0);
    }
    for (int i = lo; i < hi; i += 2) {
        float4 kn0 = {0,0,0,0}, vn0 = {0,0,0,0}, kn1 = {0,0,0,0}, vn1 = {0,0,0,0};
        if (i + 2 < hi) {
            int sr = slist[i + 2];
            kn0 = ld4(kb + (size_t)sr * HC1 + c0); vn0 = ld4(vb + (size_t)sr * HC1 + c0);
        }
        if (i + 3 < hi) {
            int sr = slist[i + 3];
            kn1 = ld4(kb + (size_t)sr * HC1 + c0); vn1 = ld4(vb + (size_t)sr * HC1 + c0);
        }
        float p0 = q.x*k0.x + q.y*k0.y + q.z*k0.z + q.w*k0.w;
        float p1 = q.x*k1.x + q.y*k1.y + q.z*k1.z + q.w*k1.w;
        #pragma unroll
        for (int off = 16; off >= 1; off >>= 1) {
            p0 += __shfl_xor(p0, off, 64);
            p1 += __shfl_xor(p1, off, 64);
        }
        const float alpha0 = p0 * scale;
        const float alpha1 = (i + 1 < hi) ? p1 * scale : -INFINITY;
        float mn = fmaxf(m, alpha0);
        float rs = __expf(m - mn);
        float pp = __expf(alpha0 - mn);
        s  = s*rs + pp;
        a0 = a0*rs + pp*v0.x; a1 = a1*rs + pp*v0.y;
        a2 = a2*rs + pp*v0.z; a3 = a3*rs + pp*v0.w;
        m = mn;
        mn = fmaxf(m, alpha1);
        rs = __expf(m - mn);
        pp = __expf(alpha1 - mn);
        s  = s*rs + pp;
        a0 = a0*rs + pp*v1.x; a1 = a1*rs + pp*v1.y;
        a2 = a2*rs + pp*v1.z; a3 = a3*rs + pp*v1.w;
        m = mn;
        k0 = kn0; v0 = vn0; k1 = kn1; v1 = vn1;
    }
    const float inv = (s > 0.f) ? 1.f/s : 0.f;
    const float att[4] = { a0*inv, a1*inv, a2*inv, a3*inv };

    const float4 x4 = ld4(xr + (size_t)n * HC1 + c0);
    const float xx[4] = { x4.x, x4.y, x4.z, x4.w };
    float d = 0.f;
    #pragma unroll
    for (int j = 0; j < 4; ++j) {
        int c = c0 + j;
        d += att[j]*wb[c] + xx[j]*wb[HC1 + c] + (att[j]-xx[j])*wb[2*HC1 + c];
    }
    d = wave_red_sum(d);
    const float beta = 1.f / (1.f + __expf(-d));
    s16x4 hv4;
    #pragma unroll
    for (int j = 0; j < 4; ++j) {
        int c = c0 + j;
        float hv = beta*xx[j] + (1.f-beta)*att[j];
        hv = (hv - mean[c]) * rsqrtf(var[c] + 1e-5f) * g[c] + bbn[c];
        hv = hv > 0.f ? hv : expm1f(hv);
        hv4[j] = f2bf(hv);
    }
    *(s16x4*)(hb + (size_t)n * HC1 + c0) = hv4;
}

// ---------- fused layer-2 attention, edge-PAIR pipelined (round-7 known-good) ----------
__global__ void __launch_bounds__(64)
attn2_k(const int* __restrict__ offs, const int* __restrict__ slist,
        const short* __restrict__ qb, const short* __restrict__ kb, const short* __restrict__ vb,
        const float* __restrict__ xr, const float* __restrict__ wb,
        float* __restrict__ outp, int colofs)
{
    const int n = blockIdx.x;
    const int lane = threadIdx.x;
    const int c0 = lane * 2;
    const int lo = offs[n], hi = offs[n+1];
    const float2 q = ld2(qb + (size_t)n * HC2 + c0);
    const float scale = 0.088388347648318447f;   // 1/sqrt(128)

    float m = -INFINITY, s = 0.f;
    float a0 = 0.f, a1 = 0.f;
    float2 k0 = {0,0}, v0 = {0,0}, k1 = {0,0}, v1 = {0,0};
    if (lo < hi) {
        int sr = slist[lo];
        k0 = ld2(kb + (size_t)sr * HC2 + c0); v0 = ld2(vb + (size_t)sr * HC2 + c0);
    }
    if (lo + 1 < hi) {
        int sr = slist[lo + 1];
        k1 = ld2(kb + (size_t)sr * HC2 + c0); v1 = ld2(vb + (size_t)sr * HC2 + c0);
    }
    for (int i = lo; i < hi; i += 2) {
        float2 kn0 = {0,0}, vn0 = {0,0}, kn1 = {0,0}, vn1 = {0,0};
        if (i + 2 < hi) {
            int sr = slist[i + 2];
            kn0 = ld2(kb + (size_t)sr * HC2 + c0); vn0 = ld2(vb + (size_t)sr * HC2 + c0);
        }
        if (i + 3 < hi) {
            int sr = slist[i + 3];
            kn1 = ld2(kb + (size_t)sr * HC2 + c0); vn1 = ld2(vb + (size_t)sr * HC2 + c0);
        }
        float p0 = q.x*k0.x + q.y*k0.y;
        float p1 = q.x*k1.x + q.y*k1.y;
        #pragma unroll
        for (int off = 32; off >= 1; off >>= 1) {
            p0 += __shfl_xor(p0, off, 64);
            p1 += __shfl_xor(p1, off, 64);
        }
        const float alpha0 = p0 * scale;
        const float alpha1 = (i + 1 < hi) ? p1 * scale : -INFINITY;
        float mn = fmaxf(m, alpha0);
        float rs = __expf(m - mn);
        float pp = __expf(alpha0 - mn);
        s  = s*rs + pp;
        a0 = a0*rs + pp*v0.x; a1 = a1*rs + pp*v0.y;
        m = mn;
        mn = fmaxf(m, alpha1);
        rs = __expf(m - mn);
        pp = __expf(alpha1 - mn);
        s  = s*rs + pp;
        a0 = a0*rs + pp*v1.x; a1 = a1*rs + pp*v1.y;
        m = mn;
        k0 = kn0; v0 = vn0; k1 = kn1; v1 = vn1;
    }
    const float inv = (s > 0.f) ? 1.f/s : 0.f;
    const float att0 = a0*inv, att1 = a1*inv;

    const float2 x2 = ld2(xr + (size_t)n * HC2 + c0);
    float d = att0*wb[c0] + att1*wb[c0+1]
            + x2.x*wb[HC2+c0] + x2.y*wb[HC2+c0+1]
            + (att0-x2.x)*wb[2*HC2+c0] + (att1-x2.y)*wb[2*HC2+c0+1];
    d = wave_red_sum(d);
    const float beta = 1.f/(1.f+__expf(-d));
    outp[(size_t)n*(RR*HC2) + colofs + c0]     = beta*x2.x + (1.f-beta)*att0;
    outp[(size_t)n*(RR*HC2) + colofs + c0 + 1] = beta*x2.y + (1.f-beta)*att1;
}

extern "C" void kernel_launch(void* const* d_in, const int* in_sizes, int n_in,
                              void* d_out, int out_size, void* d_ws, size_t ws_size,
                              hipStream_t stream)
{
    const float* features = (const float*)d_in[0];
    const int*   n_ids    = (const int*)d_in[1];
    const int*   ei1      = (const int*)d_in[2];
    const int*   ei2      = (const int*)d_in[3];
    const float* wq1 = (const float*)d_in[4];  const float* bq1 = (const float*)d_in[5];
    const float* wk1 = (const float*)d_in[6];  const float* bk1 = (const float*)d_in[7];
    const float* wv1 = (const float*)d_in[8];  const float* bv1 = (const float*)d_in[9];
    const float* ws1 = (const float*)d_in[10]; const float* bs1 = (const float*)d_in[11];
    const float* wbeta1 = (const float*)d_in[12];
    const float* bn_g = (const float*)d_in[13]; const float* bn_b = (const float*)d_in[14];
    const float* bn_m = (const float*)d_in[15]; const float* bn_v = (const float*)d_in[16];
    const float* wq2 = (const float*)d_in[17]; const float* bq2 = (const float*)d_in[18];
    const float* wk2 = (const float*)d_in[19]; const float* bk2 = (const float*)d_in[20];
    const float* wv2 = (const float*)d_in[21]; const float* bv2 = (const float*)d_in[22];
    const float* ws2 = (const float*)d_in[23]; const float* bs2 = (const float*)d_in[24];
    const float* wbeta2 = (const float*)d_in[25];
    float* outp = (float*)d_out;

    char* p = (char*)d_ws;
    auto alloc = [&](size_t bytes) { char* q = p; p += (bytes + 255) & ~(size_t)255; return q; };
    short* k1b  = (short*)alloc(sizeof(short)*(size_t)NN0*HC1);   // 41 MB
    short* v1b  = (short*)alloc(sizeof(short)*(size_t)NN0*HC1);   // 41 MB
    short* q1b  = (short*)alloc(sizeof(short)*(size_t)NN1*HC1);
    float* xr1  = (float*)alloc(sizeof(float)*(size_t)NN1*HC1);
    short* hbf  = (short*)alloc(sizeof(short)*(size_t)NN1*HC1);
    short* xbf  = (short*)alloc(sizeof(short)*(size_t)NTOT*FIN);
    short* wt1  = (short*)alloc(sizeof(short)*(size_t)RR*4*FIN*HC1);
    short* wt2  = (short*)alloc(sizeof(short)*(size_t)RR*4*HC1*HC2);
    short* k2b  = (short*)alloc(sizeof(short)*(size_t)NN1*HC2);
    short* v2b  = (short*)alloc(sizeof(short)*(size_t)NN1*HC2);
    short* q2b  = (short*)alloc(sizeof(short)*(size_t)NB*HC2);
    float* xr2  = (float*)alloc(sizeof(float)*(size_t)NB*HC2);
    // batched CSR state for ALL replicas (built once up front)
    int* cnt1   = (int*)alloc(sizeof(int)*(size_t)RR*NN1);        // also 'cur'
    int* offs1  = (int*)alloc(sizeof(int)*(size_t)RR*(NN1+1));
    int* cur1   = (int*)alloc(sizeof(int)*(size_t)RR*NN1);
    int* slist1 = (int*)alloc(sizeof(int)*(size_t)RR*NE1);
    int* cnt2   = (int*)alloc(sizeof(int)*(size_t)RR*NB);
    int* offs2  = (int*)alloc(sizeof(int)*(size_t)RR*(NB+1));
    int* cur2   = (int*)alloc(sizeof(int)*(size_t)RR*NB);
    int* slist2 = (int*)alloc(sizeof(int)*(size_t)RR*NE2);
    (void)ws_size; (void)in_sizes; (void)n_in; (void)out_size;

    // ---- prologue: conversions + weight packing ----
    fcvt_k<<<(NTOT*FIN/4 + 255)/256, 256, 0, stream>>>(features, xbf, NTOT*FIN/4);
    {
        dim3 g1(128, 4, RR);
        wpack_k<FIN, HC1><<<g1, 256, 0, stream>>>(wq1, wk1, wv1, ws1, wt1);
        dim3 g2(128, 4, RR);
        wpack_k<HC1, HC2><<<g2, 256, 0, stream>>>(wq2, wk2, wv2, ws2, wt2);
    }

    // ---- all CSR builds, batched over replicas (7 dispatches total) ----
    // cnt1 and cnt2 are adjacent allocations; one memset covers both (256B-aligned gap is fine to clear).
    hipMemsetAsync(cnt1, 0, (char*)(cnt2 + (size_t)RR*NB) - (char*)cnt1, stream);
    {
        dim3 gh1(512, RR), gh2(256, RR);
        hist_b<<<gh1, 256, 0, stream>>>(ei1, NE1, cnt1, NN1);
        hist_b<<<gh2, 256, 0, stream>>>(ei2, NE2, cnt2, NB);
        exscan_b<<<RR, 256, 0, stream>>>(cnt1, NN1, offs1, cur1);
        exscan_b<<<RR, 256, 0, stream>>>(cnt2, NB, offs2, cur2);
        scatter_b<<<gh1, 256, 0, stream>>>(ei1, NE1, cur1, NN1, slist1);
        scatter_b<<<gh2, 256, 0, stream>>>(ei2, NE2, cur2, NB, slist2);
    }

    const size_t WSZ = (size_t)FIN*HC1;

    for (int r = 0; r < RR; ++r) {
        const int* nid  = n_ids + (size_t)r*NN0;
        const short* ptq1 = wt1 + ((size_t)r*4 + 0)*WSZ;
        const short* ptk1 = wt1 + ((size_t)r*4 + 1)*WSZ;
        const short* ptv1 = wt1 + ((size_t)r*4 + 2)*WSZ;
        const short* pts1 = wt1 + ((size_t)r*4 + 3)*WSZ;
        const short* ptq2 = wt2 + ((size_t)r*4 + 0)*WSZ;
        const short* ptk2 = wt2 + ((size_t)r*4 + 1)*WSZ;
        const short* ptv2 = wt2 + ((size_t)r*4 + 2)*WSZ;
        const short* pts2 = wt2 + ((size_t)r*4 + 3)*WSZ;

        // ---- layer 1 projections (MFMA, fused gather, bf16 out) ----
        gemm2l<FIN, HC1, short, short><<<NN0/32, 256, 0, stream>>>(
            xbf, FIN, nid, ptk1, bk1 + r*HC1, k1b, ptv1, bv1 + r*HC1, v1b);
        gemm2l<FIN, HC1, short, float><<<NN1/32, 256, 0, stream>>>(
            xbf, FIN, nid, ptq1, bq1 + r*HC1, q1b, pts1, bs1 + r*HC1, xr1);

        // ---- layer 1 fused attention + epilogue ----
        attn1_k<<<NN1, 64, 0, stream>>>(offs1 + (size_t)r*(NN1+1), slist1 + (size_t)r*NE1,
            q1b, k1b, v1b, xr1,
            wbeta1 + (size_t)r*3*HC1,
            bn_g + (size_t)r*HC1, bn_b + (size_t)r*HC1,
            bn_m + (size_t)r*HC1, bn_v + (size_t)r*HC1, hbf);

        // ---- layer 2 projections (MFMA, bf16 out for k/v/q) ----
        gemm2l<HC1, HC2, short, short><<<NN1/32, 256, 0, stream>>>(
            hbf, HC1, nullptr, ptk2, bk2 + r*HC2, k2b, ptv2, bv2 + r*HC2, v2b);
        gemm2l<HC1, HC2, short, float><<<NB/32, 256, 0, stream>>>(
            hbf, HC1, nullptr, ptq2, bq2 + r*HC2, q2b, pts2, bs2 + r*HC2, xr2);

        // ---- layer 2 fused attention + output ----
        attn2_k<<<NB, 64, 0, stream>>>(offs2 + (size_t)r*(NB+1), slist2 + (size_t)r*NE2,
            q2b, k2b, v2b, xr2,
            wbeta2 + (size_t)r*3*HC2, outp, r*HC2);
    }
}